// Round 1
// baseline (2497.508 us; speedup 1.0000x reference)
//
#include <hip/hip_runtime.h>
#include <cstdint>
#include <cstddef>

// B=4, S=2048, D=512, H=8, DK=64.
// Outputs: out [B,S,D] then attention [B,H,S,S], both fp32, concatenated in d_out.
//
// NOTE: the "organic" bias is added uniformly across the key axis per query row,
// and softmax is shift-invariant per row => it cancels exactly (reference also
// subtracts the row max). Worg/borg/is_organic are therefore unused.
//
// ws layout (floats): Q[B,H,S,DK] | K[B,H,S,DK] | V[B,H,S,DK] | C[B,S,D]  = 64 MB.

static constexpr int B  = 4;
static constexpr int S  = 2048;
static constexpr int D  = 512;
static constexpr int H  = 8;
static constexpr int DK = 64;
static constexpr int N  = B * S;   // 8192
static constexpr int BH = B * H;   // 32

#define FMA16(av, bv)                                                        \
  {                                                                          \
    const float a_[4] = {(av).x, (av).y, (av).z, (av).w};                    \
    const float b_[4] = {(bv).x, (bv).y, (bv).z, (bv).w};                    \
    _Pragma("unroll") for (int i2 = 0; i2 < 4; ++i2)                         \
        _Pragma("unroll") for (int j2 = 0; j2 < 4; ++j2)                     \
            acc[i2][j2] = fmaf(a_[i2], b_[j2], acc[i2][j2]);                 \
  }

// ---------------- Y = X @ W^T + bias  (X:[N,512], W:[512,512] row-major) ---
// head_layout=1: Y[b,h,s,dk]; head_layout=0: Y[n, o] flat.
__global__ __launch_bounds__(256) void proj_kernel(
    const float* __restrict__ X, const float* __restrict__ W,
    const float* __restrict__ bias, float* __restrict__ Y, int head_layout)
{
  __shared__ float As[16][64];  // As[k][row]  (transposed)
  __shared__ float Bs[16][64];  // Bs[k][out]  (transposed)
  const int tid = threadIdx.x;
  const int tx = tid & 15, ty = tid >> 4;
  const int row0 = blockIdx.x * 64, col0 = blockIdx.y * 64;
  const int r = tid >> 2, c4 = (tid & 3) * 4;

  float acc[4][4] = {};
  for (int kc = 0; kc < D; kc += 16) {
    const float4 xa = *(const float4*)&X[(size_t)(row0 + r) * D + kc + c4];
    const float4 wb = *(const float4*)&W[(size_t)(col0 + r) * D + kc + c4];
    __syncthreads();
    As[c4 + 0][r] = xa.x; As[c4 + 1][r] = xa.y; As[c4 + 2][r] = xa.z; As[c4 + 3][r] = xa.w;
    Bs[c4 + 0][r] = wb.x; Bs[c4 + 1][r] = wb.y; Bs[c4 + 2][r] = wb.z; Bs[c4 + 3][r] = wb.w;
    __syncthreads();
#pragma unroll
    for (int c = 0; c < 16; ++c) {
      const float4 av = *(const float4*)&As[c][ty * 4];
      const float4 bv = *(const float4*)&Bs[c][tx * 4];
      FMA16(av, bv);
    }
  }

  const int ocol = col0 + tx * 4;
  const float bs0 = bias[ocol + 0], bs1 = bias[ocol + 1];
  const float bs2 = bias[ocol + 2], bs3 = bias[ocol + 3];
#pragma unroll
  for (int i2 = 0; i2 < 4; ++i2) {
    const int row = row0 + ty * 4 + i2;
    size_t dst;
    if (head_layout) {
      const int bb = row >> 11, ss = row & (S - 1);
      const int hh = col0 >> 6;
      dst = ((size_t)(bb * H + hh) * S + ss) * DK + (tx * 4);
    } else {
      dst = (size_t)row * D + ocol;
    }
    const float4 st = make_float4(acc[i2][0] + bs0, acc[i2][1] + bs1,
                                  acc[i2][2] + bs2, acc[i2][3] + bs3);
    *(float4*)&Y[dst] = st;
  }
}

// ---------------- raw scores: attn[bh,q,k] = mask ? (Q.K)/8 : -1e9 ----------
__global__ __launch_bounds__(256) void scores_kernel(
    const float* __restrict__ Q, const float* __restrict__ Kp,
    const int* __restrict__ mask, float* __restrict__ attn)
{
  __shared__ float Qs[64][68];  // Qs[d][q]
  __shared__ float Ks[64][68];  // Ks[d][k]
  const int tid = threadIdx.x;
  const int tx = tid & 15, ty = tid >> 4;
  const int q0 = blockIdx.x * 64, k0 = blockIdx.y * 64;
  const int bh = (int)blockIdx.z, b = bh >> 3;
  const float* __restrict__ Qh = Q + (size_t)bh * S * DK;
  const float* __restrict__ Kh = Kp + (size_t)bh * S * DK;

  // stage 64x64 tiles, transposed via 4x4 register transpose
  const int rq4 = (tid & 15) * 4;  // row quad
  const int cd4 = (tid >> 4) * 4;  // d-col quad
  float4 qr[4], kr[4];
#pragma unroll
  for (int rr = 0; rr < 4; ++rr) {
    qr[rr] = *(const float4*)&Qh[(size_t)(q0 + rq4 + rr) * DK + cd4];
    kr[rr] = *(const float4*)&Kh[(size_t)(k0 + rq4 + rr) * DK + cd4];
  }
  *(float4*)&Qs[cd4 + 0][rq4] = make_float4(qr[0].x, qr[1].x, qr[2].x, qr[3].x);
  *(float4*)&Qs[cd4 + 1][rq4] = make_float4(qr[0].y, qr[1].y, qr[2].y, qr[3].y);
  *(float4*)&Qs[cd4 + 2][rq4] = make_float4(qr[0].z, qr[1].z, qr[2].z, qr[3].z);
  *(float4*)&Qs[cd4 + 3][rq4] = make_float4(qr[0].w, qr[1].w, qr[2].w, qr[3].w);
  *(float4*)&Ks[cd4 + 0][rq4] = make_float4(kr[0].x, kr[1].x, kr[2].x, kr[3].x);
  *(float4*)&Ks[cd4 + 1][rq4] = make_float4(kr[0].y, kr[1].y, kr[2].y, kr[3].y);
  *(float4*)&Ks[cd4 + 2][rq4] = make_float4(kr[0].z, kr[1].z, kr[2].z, kr[3].z);
  *(float4*)&Ks[cd4 + 3][rq4] = make_float4(kr[0].w, kr[1].w, kr[2].w, kr[3].w);
  __syncthreads();

  float acc[4][4] = {};
#pragma unroll
  for (int d = 0; d < 64; ++d) {
    const float4 av = *(const float4*)&Qs[d][ty * 4];
    const float4 bv = *(const float4*)&Ks[d][tx * 4];
    FMA16(av, bv);
  }

  const int kbase = k0 + tx * 4;
  const int m0 = mask[b * S + kbase + 0];
  const int m1 = mask[b * S + kbase + 1];
  const int m2 = mask[b * S + kbase + 2];
  const int m3 = mask[b * S + kbase + 3];
#pragma unroll
  for (int i2 = 0; i2 < 4; ++i2) {
    const int q = q0 + ty * 4 + i2;
    float4 st;
    st.x = m0 ? acc[i2][0] * 0.125f : -1e9f;
    st.y = m1 ? acc[i2][1] * 0.125f : -1e9f;
    st.z = m2 ? acc[i2][2] * 0.125f : -1e9f;
    st.w = m3 ? acc[i2][3] * 0.125f : -1e9f;
    *(float4*)&attn[((size_t)bh * S + q) * S + kbase] = st;
  }
}

// ---------------- in-place row softmax over 2048 cols ----------------------
__global__ __launch_bounds__(256) void softmax_kernel(float* __restrict__ attn)
{
  const int row = (int)blockIdx.x;
  float* __restrict__ p = attn + (size_t)row * S;
  const int tid = threadIdx.x;
  float4 a = *(const float4*)&p[tid * 4];
  float4 c = *(const float4*)&p[1024 + tid * 4];

  float m = fmaxf(fmaxf(fmaxf(a.x, a.y), fmaxf(a.z, a.w)),
                  fmaxf(fmaxf(c.x, c.y), fmaxf(c.z, c.w)));
#pragma unroll
  for (int off = 32; off > 0; off >>= 1) m = fmaxf(m, __shfl_xor(m, off));
  __shared__ float redm[4], reds[4];
  const int wv = tid >> 6, ln = tid & 63;
  if (ln == 0) redm[wv] = m;
  __syncthreads();
  m = fmaxf(fmaxf(redm[0], redm[1]), fmaxf(redm[2], redm[3]));

  a.x = __expf(a.x - m); a.y = __expf(a.y - m);
  a.z = __expf(a.z - m); a.w = __expf(a.w - m);
  c.x = __expf(c.x - m); c.y = __expf(c.y - m);
  c.z = __expf(c.z - m); c.w = __expf(c.w - m);
  float ssum = a.x + a.y + a.z + a.w + c.x + c.y + c.z + c.w;
#pragma unroll
  for (int off = 32; off > 0; off >>= 1) ssum += __shfl_xor(ssum, off);
  if (ln == 0) reds[wv] = ssum;
  __syncthreads();
  const float inv = 1.0f / (reds[0] + reds[1] + reds[2] + reds[3]);

  a.x *= inv; a.y *= inv; a.z *= inv; a.w *= inv;
  c.x *= inv; c.y *= inv; c.z *= inv; c.w *= inv;
  *(float4*)&p[tid * 4] = a;
  *(float4*)&p[1024 + tid * 4] = c;
}

// ---------------- context[b,s,h*64+d] = sum_k attn[bh,q,k] * V[bh,k,d] ------
__global__ __launch_bounds__(256) void context_kernel(
    const float* __restrict__ attn, const float* __restrict__ V,
    float* __restrict__ C)
{
  __shared__ float Ps[16][64];  // Ps[k][q]
  __shared__ float Vs[16][64];  // Vs[k][d]
  const int tid = threadIdx.x;
  const int tx = tid & 15, ty = tid >> 4;
  const int q0 = blockIdx.x * 64;
  const int bh = (int)blockIdx.z, b = bh >> 3, h = bh & 7;
  const float* __restrict__ Ah = attn + (size_t)bh * S * S;
  const float* __restrict__ Vh = V + (size_t)bh * S * DK;
  const int pr = tid >> 2, pk4 = (tid & 3) * 4;
  const int vr = tid >> 4, vc4 = (tid & 15) * 4;

  float acc[4][4] = {};
  for (int kc = 0; kc < S; kc += 16) {
    const float4 pa = *(const float4*)&Ah[(size_t)(q0 + pr) * S + kc + pk4];
    const float4 va = *(const float4*)&Vh[(size_t)(kc + vr) * DK + vc4];
    __syncthreads();
    Ps[pk4 + 0][pr] = pa.x; Ps[pk4 + 1][pr] = pa.y;
    Ps[pk4 + 2][pr] = pa.z; Ps[pk4 + 3][pr] = pa.w;
    *(float4*)&Vs[vr][vc4] = va;
    __syncthreads();
#pragma unroll
    for (int kk = 0; kk < 16; ++kk) {
      const float4 av = *(const float4*)&Ps[kk][ty * 4];
      const float4 bv = *(const float4*)&Vs[kk][tx * 4];
      FMA16(av, bv);
    }
  }

#pragma unroll
  for (int i2 = 0; i2 < 4; ++i2) {
    const int q = q0 + ty * 4 + i2;
    const size_t dst = ((size_t)(b * S + q)) * D + h * DK + tx * 4;
    *(float4*)&C[dst] = make_float4(acc[i2][0], acc[i2][1], acc[i2][2], acc[i2][3]);
  }
}

extern "C" void kernel_launch(void* const* d_in, const int* in_sizes, int n_in,
                              void* d_out, int out_size, void* d_ws, size_t ws_size,
                              hipStream_t stream)
{
  (void)in_sizes; (void)n_in; (void)out_size; (void)ws_size;
  const float* query = (const float*)d_in[0];
  const float* key   = (const float*)d_in[1];
  const float* value = (const float*)d_in[2];
  const int*   mask  = (const int*)d_in[3];
  // d_in[4] = is_organic (unused: cancels in softmax)
  const float* Wq = (const float*)d_in[5];
  const float* bq = (const float*)d_in[6];
  const float* Wk = (const float*)d_in[7];
  const float* bk = (const float*)d_in[8];
  const float* Wv = (const float*)d_in[9];
  const float* bv = (const float*)d_in[10];
  const float* Wo = (const float*)d_in[11];
  const float* bo = (const float*)d_in[12];
  // d_in[13]=Worg, d_in[14]=borg (unused: cancel in softmax)

  float* out  = (float*)d_out;
  float* attn = out + (size_t)N * D;

  float* Qb = (float*)d_ws;
  float* Kb = Qb + (size_t)N * D;
  float* Vb = Kb + (size_t)N * D;
  float* Cb = Vb + (size_t)N * D;

  const dim3 blk(256);
  proj_kernel<<<dim3(N / 64, D / 64), blk, 0, stream>>>(query, Wq, bq, Qb, 1);
  proj_kernel<<<dim3(N / 64, D / 64), blk, 0, stream>>>(key,   Wk, bk, Kb, 1);
  proj_kernel<<<dim3(N / 64, D / 64), blk, 0, stream>>>(value, Wv, bv, Vb, 1);
  scores_kernel<<<dim3(S / 64, S / 64, BH), blk, 0, stream>>>(Qb, Kb, mask, attn);
  softmax_kernel<<<dim3(BH * S), blk, 0, stream>>>(attn);
  context_kernel<<<dim3(S / 64, 1, BH), blk, 0, stream>>>(attn, Vb, Cb);
  proj_kernel<<<dim3(N / 64, D / 64), blk, 0, stream>>>(Cb, Wo, bo, out, 0);
}